// Round 1
// baseline (448.715 us; speedup 1.0000x reference)
//
#include <hip/hip_runtime.h>

#define N_NODES 50000
#define D 128
#define N_EDGES 600000
#define BN_EPS 1e-5f

// ---------------------------------------------------------------------------
// Zero agg (6.4M floats) and stats (256 floats)
// ---------------------------------------------------------------------------
__global__ void zero_kernel(float* __restrict__ agg, float* __restrict__ stats) {
    int gid = blockIdx.x * blockDim.x + threadIdx.x;
    const int n4 = N_NODES * D / 4;  // 1,600,000 float4s
    if (gid < n4) {
        ((float4*)agg)[gid] = make_float4(0.f, 0.f, 0.f, 0.f);
    }
    if (gid < 64) {
        ((float4*)stats)[gid] = make_float4(0.f, 0.f, 0.f, 0.f);
    }
}

// ---------------------------------------------------------------------------
// Scatter-add: agg[dst] += feature[src] for each edge
// One thread per (edge, feature) pair: 76.8M threads
// ---------------------------------------------------------------------------
__global__ void scatter_kernel(const float* __restrict__ feat,
                               const int* __restrict__ ei,
                               float* __restrict__ agg) {
    int gid = blockIdx.x * blockDim.x + threadIdx.x;
    if (gid >= N_EDGES * D) return;
    int e = gid >> 7;
    int f = gid & 127;
    int src = ei[e];
    int dst = ei[N_EDGES + e];
    atomicAdd(&agg[dst * D + f], feat[src * D + f]);
}

// ---------------------------------------------------------------------------
// GEMM1: out = relu((feat + agg) @ W + bias)
// Block: 256 threads, 32 rows x 128 cols tile, 4x4 per thread.
// W staged in LDS in two 64-row K-chunks (32KB) + 16KB h tile = 48KB LDS.
// ---------------------------------------------------------------------------
__global__ __launch_bounds__(256) void gemm1_kernel(
    const float* __restrict__ feat, const float* __restrict__ agg,
    const float* __restrict__ W, const float* __restrict__ bias,
    float* __restrict__ out)
{
    __shared__ float Wlds[64 * 128];   // 32KB, one K-chunk
    __shared__ float hlds[32 * 128];   // 16KB

    const int tid = threadIdx.x;
    const int cg = tid & 31;          // col group: c0 = cg*4
    const int rg = tid >> 5;          // row group: rows rg*4 .. rg*4+3
    const int c0 = cg * 4;
    const int rowBase = blockIdx.x * 32;

    // Load h tile = feat + agg (guard rows >= N with zeros)
    for (int i = tid; i < 32 * 128 / 4; i += 256) {
        int row = i >> 5;
        int col = (i & 31) * 4;
        int r = rowBase + row;
        float4 v = make_float4(0.f, 0.f, 0.f, 0.f);
        if (r < N_NODES) {
            float4 fv = *(const float4*)&feat[r * 128 + col];
            float4 av = *(const float4*)&agg[r * 128 + col];
            v = make_float4(fv.x + av.x, fv.y + av.y, fv.z + av.z, fv.w + av.w);
        }
        *(float4*)&hlds[i * 4] = v;
    }

    float acc[4][4] = {{0.f}};

    for (int kc = 0; kc < 2; ++kc) {
        __syncthreads();  // hlds ready (kc=0) / Wlds chunk fully consumed (kc=1)
        for (int i = tid; i < 64 * 128 / 4; i += 256) {
            *(float4*)&Wlds[i * 4] = *(const float4*)&W[kc * 64 * 128 + i * 4];
        }
        __syncthreads();
        #pragma unroll 16
        for (int k = 0; k < 64; ++k) {
            float4 w = *(float4*)&Wlds[k * 128 + c0];
            float h0 = hlds[(rg * 4 + 0) * 128 + kc * 64 + k];
            float h1 = hlds[(rg * 4 + 1) * 128 + kc * 64 + k];
            float h2 = hlds[(rg * 4 + 2) * 128 + kc * 64 + k];
            float h3 = hlds[(rg * 4 + 3) * 128 + kc * 64 + k];
            acc[0][0] += h0 * w.x; acc[0][1] += h0 * w.y; acc[0][2] += h0 * w.z; acc[0][3] += h0 * w.w;
            acc[1][0] += h1 * w.x; acc[1][1] += h1 * w.y; acc[1][2] += h1 * w.z; acc[1][3] += h1 * w.w;
            acc[2][0] += h2 * w.x; acc[2][1] += h2 * w.y; acc[2][2] += h2 * w.z; acc[2][3] += h2 * w.w;
            acc[3][0] += h3 * w.x; acc[3][1] += h3 * w.y; acc[3][2] += h3 * w.z; acc[3][3] += h3 * w.w;
        }
    }

    float4 bv = *(const float4*)&bias[c0];
    #pragma unroll
    for (int j = 0; j < 4; ++j) {
        int r = rowBase + rg * 4 + j;
        if (r < N_NODES) {
            float4 o;
            o.x = fmaxf(acc[j][0] + bv.x, 0.f);
            o.y = fmaxf(acc[j][1] + bv.y, 0.f);
            o.z = fmaxf(acc[j][2] + bv.z, 0.f);
            o.w = fmaxf(acc[j][3] + bv.w, 0.f);
            *(float4*)&out[r * 128 + c0] = o;
        }
    }
}

// ---------------------------------------------------------------------------
// GEMM2: y = relu(h1 @ W2 + b2), store y, accumulate BN column sums/sumsq.
// ---------------------------------------------------------------------------
__global__ __launch_bounds__(256) void gemm2_kernel(
    const float* __restrict__ h1,
    const float* __restrict__ W, const float* __restrict__ bias,
    float* __restrict__ y, float* __restrict__ stats)
{
    __shared__ float Wlds[64 * 128];
    __shared__ float hlds[32 * 128];

    const int tid = threadIdx.x;
    const int cg = tid & 31;
    const int rg = tid >> 5;
    const int c0 = cg * 4;
    const int rowBase = blockIdx.x * 32;

    for (int i = tid; i < 32 * 128 / 4; i += 256) {
        int row = i >> 5;
        int col = (i & 31) * 4;
        int r = rowBase + row;
        float4 v = make_float4(0.f, 0.f, 0.f, 0.f);
        if (r < N_NODES) {
            v = *(const float4*)&h1[r * 128 + col];
        }
        *(float4*)&hlds[i * 4] = v;
    }

    float acc[4][4] = {{0.f}};

    for (int kc = 0; kc < 2; ++kc) {
        __syncthreads();
        for (int i = tid; i < 64 * 128 / 4; i += 256) {
            *(float4*)&Wlds[i * 4] = *(const float4*)&W[kc * 64 * 128 + i * 4];
        }
        __syncthreads();
        #pragma unroll 16
        for (int k = 0; k < 64; ++k) {
            float4 w = *(float4*)&Wlds[k * 128 + c0];
            float h0 = hlds[(rg * 4 + 0) * 128 + kc * 64 + k];
            float h1v = hlds[(rg * 4 + 1) * 128 + kc * 64 + k];
            float h2 = hlds[(rg * 4 + 2) * 128 + kc * 64 + k];
            float h3 = hlds[(rg * 4 + 3) * 128 + kc * 64 + k];
            acc[0][0] += h0 * w.x;  acc[0][1] += h0 * w.y;  acc[0][2] += h0 * w.z;  acc[0][3] += h0 * w.w;
            acc[1][0] += h1v * w.x; acc[1][1] += h1v * w.y; acc[1][2] += h1v * w.z; acc[1][3] += h1v * w.w;
            acc[2][0] += h2 * w.x;  acc[2][1] += h2 * w.y;  acc[2][2] += h2 * w.z;  acc[2][3] += h2 * w.w;
            acc[3][0] += h3 * w.x;  acc[3][1] += h3 * w.y;  acc[3][2] += h3 * w.z;  acc[3][3] += h3 * w.w;
        }
    }

    float4 bv = *(const float4*)&bias[c0];
    float ps[4] = {0.f, 0.f, 0.f, 0.f};
    float pq[4] = {0.f, 0.f, 0.f, 0.f};
    #pragma unroll
    for (int j = 0; j < 4; ++j) {
        int r = rowBase + rg * 4 + j;
        if (r < N_NODES) {
            float4 o;
            o.x = fmaxf(acc[j][0] + bv.x, 0.f);
            o.y = fmaxf(acc[j][1] + bv.y, 0.f);
            o.z = fmaxf(acc[j][2] + bv.z, 0.f);
            o.w = fmaxf(acc[j][3] + bv.w, 0.f);
            *(float4*)&y[r * 128 + c0] = o;
            ps[0] += o.x; ps[1] += o.y; ps[2] += o.z; ps[3] += o.w;
            pq[0] += o.x * o.x; pq[1] += o.y * o.y; pq[2] += o.z * o.z; pq[3] += o.w * o.w;
        }
    }

    // Block reduction of column partials via LDS (reuse hlds), then atomics.
    __syncthreads();
    float* sums = hlds;          // [8][128]
    float* sqs  = hlds + 1024;   // [8][128]
    *(float4*)&sums[rg * 128 + c0] = make_float4(ps[0], ps[1], ps[2], ps[3]);
    *(float4*)&sqs[rg * 128 + c0]  = make_float4(pq[0], pq[1], pq[2], pq[3]);
    __syncthreads();
    if (tid < 128) {
        float s = 0.f, q = 0.f;
        #pragma unroll
        for (int g = 0; g < 8; ++g) {
            s += sums[g * 128 + tid];
            q += sqs[g * 128 + tid];
        }
        atomicAdd(&stats[tid], s);
        atomicAdd(&stats[128 + tid], q);
    }
}

// ---------------------------------------------------------------------------
// BatchNorm apply, in place on y (= d_out)
// ---------------------------------------------------------------------------
__global__ void bn_kernel(float* __restrict__ y,
                          const float* __restrict__ stats,
                          const float* __restrict__ gamma,
                          const float* __restrict__ beta)
{
    int gid = blockIdx.x * blockDim.x + threadIdx.x;
    const int n4 = N_NODES * D / 4;
    if (gid >= n4) return;
    int c0 = (gid << 2) & 127;
    const float inv_n = 1.0f / (float)N_NODES;
    float4 v = ((float4*)y)[gid];
    float4 s = *(const float4*)&stats[c0];
    float4 q = *(const float4*)&stats[128 + c0];
    float4 g = *(const float4*)&gamma[c0];
    float4 b = *(const float4*)&beta[c0];

    float m, var;
    m = s.x * inv_n; var = q.x * inv_n - m * m;
    v.x = (v.x - m) * rsqrtf(var + BN_EPS) * g.x + b.x;
    m = s.y * inv_n; var = q.y * inv_n - m * m;
    v.y = (v.y - m) * rsqrtf(var + BN_EPS) * g.y + b.y;
    m = s.z * inv_n; var = q.z * inv_n - m * m;
    v.z = (v.z - m) * rsqrtf(var + BN_EPS) * g.z + b.z;
    m = s.w * inv_n; var = q.w * inv_n - m * m;
    v.w = (v.w - m) * rsqrtf(var + BN_EPS) * g.w + b.w;

    ((float4*)y)[gid] = v;
}

// ---------------------------------------------------------------------------
extern "C" void kernel_launch(void* const* d_in, const int* in_sizes, int n_in,
                              void* d_out, int out_size, void* d_ws, size_t ws_size,
                              hipStream_t stream) {
    const float* feature = (const float*)d_in[0];
    const int*   ei      = (const int*)d_in[1];
    const float* W1      = (const float*)d_in[2];
    const float* b1      = (const float*)d_in[3];
    const float* W2      = (const float*)d_in[4];
    const float* b2      = (const float*)d_in[5];
    const float* gamma   = (const float*)d_in[6];
    const float* beta    = (const float*)d_in[7];
    float* out = (float*)d_out;

    float* agg   = (float*)d_ws;            // 6,400,000 floats
    float* h1    = agg + N_NODES * D;       // 6,400,000 floats
    float* stats = h1 + N_NODES * D;        // 256 floats (sum | sumsq)

    // 1. zero agg + stats
    {
        int n4 = N_NODES * D / 4;
        int blocks = (n4 + 255) / 256;
        zero_kernel<<<blocks, 256, 0, stream>>>(agg, stats);
    }
    // 2. scatter-add
    {
        int total = N_EDGES * D;
        int blocks = (total + 255) / 256;
        scatter_kernel<<<blocks, 256, 0, stream>>>(feature, ei, agg);
    }
    // 3. GEMM1 + ReLU
    {
        int blocks = (N_NODES + 31) / 32;
        gemm1_kernel<<<blocks, 256, 0, stream>>>(feature, agg, W1, b1, h1);
    }
    // 4. GEMM2 + ReLU + BN stats
    {
        int blocks = (N_NODES + 31) / 32;
        gemm2_kernel<<<blocks, 256, 0, stream>>>(h1, W2, b2, out, stats);
    }
    // 5. BN apply
    {
        int n4 = N_NODES * D / 4;
        int blocks = (n4 + 255) / 256;
        bn_kernel<<<blocks, 256, 0, stream>>>(out, stats, gamma, beta);
    }
}

// Round 2
// 319.058 us; speedup vs baseline: 1.4064x; 1.4064x over previous
//
#include <hip/hip_runtime.h>

#define N_NODES 50000
#define D 128
#define N_EDGES 600000
#define BN_EPS 1e-5f
#define SCAN_BLOCKS 49  // ceil(50000/1024)

// ---------------------------------------------------------------------------
// Zero counts (50000 ints) and stats (256 floats)
// ---------------------------------------------------------------------------
__global__ void zero_kernel(int* __restrict__ cnt, float* __restrict__ stats) {
    int gid = blockIdx.x * blockDim.x + threadIdx.x;
    if (gid < N_NODES) cnt[gid] = 0;
    if (gid < 256) stats[gid] = 0.f;
}

// ---------------------------------------------------------------------------
// Histogram of dst
// ---------------------------------------------------------------------------
__global__ void hist_kernel(const int* __restrict__ ei, int* __restrict__ cnt) {
    int e = blockIdx.x * blockDim.x + threadIdx.x;
    if (e >= N_EDGES) return;
    atomicAdd(&cnt[ei[N_EDGES + e]], 1);
}

// ---------------------------------------------------------------------------
// Scan pass A: per-block (1024 elems) exclusive scan + block sums
// ---------------------------------------------------------------------------
__global__ __launch_bounds__(1024) void scanA_kernel(const int* __restrict__ cnt,
                                                     int* __restrict__ offs,
                                                     int* __restrict__ bsum) {
    __shared__ int buf[1024];
    int tid = threadIdx.x;
    int i = blockIdx.x * 1024 + tid;
    int v = (i < N_NODES) ? cnt[i] : 0;
    buf[tid] = v;
    __syncthreads();
    for (int off = 1; off < 1024; off <<= 1) {
        int t = (tid >= off) ? buf[tid - off] : 0;
        __syncthreads();
        buf[tid] += t;
        __syncthreads();
    }
    int incl = buf[tid];
    if (i < N_NODES) offs[i] = incl - v;   // block-local exclusive
    if (tid == 1023) bsum[blockIdx.x] = incl;
}

// ---------------------------------------------------------------------------
// Scan pass B: scan the block sums (SCAN_BLOCKS values), single thread
// ---------------------------------------------------------------------------
__global__ void scanB_kernel(int* __restrict__ bsum) {
    if (threadIdx.x == 0 && blockIdx.x == 0) {
        int running = 0;
        for (int b = 0; b < SCAN_BLOCKS; ++b) {
            int t = bsum[b];
            bsum[b] = running;
            running += t;
        }
    }
}

// ---------------------------------------------------------------------------
// Scan pass C: add block offsets, produce final offs + cursor copy
// ---------------------------------------------------------------------------
__global__ __launch_bounds__(1024) void scanC_kernel(int* __restrict__ offs,
                                                     const int* __restrict__ bsum,
                                                     int* __restrict__ cursor) {
    int i = blockIdx.x * 1024 + threadIdx.x;
    if (i == 0) offs[N_NODES] = N_EDGES;
    if (i >= N_NODES) return;
    int v = offs[i] + bsum[i >> 10];
    offs[i] = v;
    cursor[i] = v;
}

// ---------------------------------------------------------------------------
// Scatter edge src indices into dst-sorted order
// ---------------------------------------------------------------------------
__global__ void scatter_idx_kernel(const int* __restrict__ ei,
                                   int* __restrict__ cursor,
                                   int* __restrict__ ssrc) {
    int e = blockIdx.x * blockDim.x + threadIdx.x;
    if (e >= N_EDGES) return;
    int src = ei[e];
    int dst = ei[N_EDGES + e];
    int pos = atomicAdd(&cursor[dst], 1);
    ssrc[pos] = src;
}

// ---------------------------------------------------------------------------
// Gather: agg[n] = sum over neighbors of feature[src]. One wave per node.
// Lane i handles feature columns [2i, 2i+1] as float2.
// ---------------------------------------------------------------------------
__global__ __launch_bounds__(256) void gather_kernel(const float* __restrict__ feat,
                                                     const int* __restrict__ offs,
                                                     const int* __restrict__ ssrc,
                                                     float* __restrict__ agg) {
    int wave = (blockIdx.x * 256 + threadIdx.x) >> 6;  // node id
    int lane = threadIdx.x & 63;
    if (wave >= N_NODES) return;
    int beg = offs[wave];
    int end = offs[wave + 1];
    float2 acc = make_float2(0.f, 0.f);
    for (int j = beg; j < end; ++j) {
        int s = ssrc[j];
        float2 v = *(const float2*)&feat[s * D + lane * 2];
        acc.x += v.x;
        acc.y += v.y;
    }
    *(float2*)&agg[wave * D + lane * 2] = acc;
}

// ---------------------------------------------------------------------------
// GEMM1: out = relu((feat + agg) @ W + bias)
// ---------------------------------------------------------------------------
__global__ __launch_bounds__(256) void gemm1_kernel(
    const float* __restrict__ feat, const float* __restrict__ agg,
    const float* __restrict__ W, const float* __restrict__ bias,
    float* __restrict__ out)
{
    __shared__ float Wlds[64 * 128];   // 32KB, one K-chunk
    __shared__ float hlds[32 * 128];   // 16KB

    const int tid = threadIdx.x;
    const int cg = tid & 31;
    const int rg = tid >> 5;
    const int c0 = cg * 4;
    const int rowBase = blockIdx.x * 32;

    for (int i = tid; i < 32 * 128 / 4; i += 256) {
        int row = i >> 5;
        int col = (i & 31) * 4;
        int r = rowBase + row;
        float4 v = make_float4(0.f, 0.f, 0.f, 0.f);
        if (r < N_NODES) {
            float4 fv = *(const float4*)&feat[r * 128 + col];
            float4 av = *(const float4*)&agg[r * 128 + col];
            v = make_float4(fv.x + av.x, fv.y + av.y, fv.z + av.z, fv.w + av.w);
        }
        *(float4*)&hlds[i * 4] = v;
    }

    float acc[4][4] = {{0.f}};

    for (int kc = 0; kc < 2; ++kc) {
        __syncthreads();
        for (int i = tid; i < 64 * 128 / 4; i += 256) {
            *(float4*)&Wlds[i * 4] = *(const float4*)&W[kc * 64 * 128 + i * 4];
        }
        __syncthreads();
        #pragma unroll 16
        for (int k = 0; k < 64; ++k) {
            float4 w = *(float4*)&Wlds[k * 128 + c0];
            float h0 = hlds[(rg * 4 + 0) * 128 + kc * 64 + k];
            float h1 = hlds[(rg * 4 + 1) * 128 + kc * 64 + k];
            float h2 = hlds[(rg * 4 + 2) * 128 + kc * 64 + k];
            float h3 = hlds[(rg * 4 + 3) * 128 + kc * 64 + k];
            acc[0][0] += h0 * w.x; acc[0][1] += h0 * w.y; acc[0][2] += h0 * w.z; acc[0][3] += h0 * w.w;
            acc[1][0] += h1 * w.x; acc[1][1] += h1 * w.y; acc[1][2] += h1 * w.z; acc[1][3] += h1 * w.w;
            acc[2][0] += h2 * w.x; acc[2][1] += h2 * w.y; acc[2][2] += h2 * w.z; acc[2][3] += h2 * w.w;
            acc[3][0] += h3 * w.x; acc[3][1] += h3 * w.y; acc[3][2] += h3 * w.z; acc[3][3] += h3 * w.w;
        }
    }

    float4 bv = *(const float4*)&bias[c0];
    #pragma unroll
    for (int j = 0; j < 4; ++j) {
        int r = rowBase + rg * 4 + j;
        if (r < N_NODES) {
            float4 o;
            o.x = fmaxf(acc[j][0] + bv.x, 0.f);
            o.y = fmaxf(acc[j][1] + bv.y, 0.f);
            o.z = fmaxf(acc[j][2] + bv.z, 0.f);
            o.w = fmaxf(acc[j][3] + bv.w, 0.f);
            *(float4*)&out[r * 128 + c0] = o;
        }
    }
}

// ---------------------------------------------------------------------------
// GEMM2: y = relu(h1 @ W2 + b2), store y, accumulate BN column sums/sumsq.
// ---------------------------------------------------------------------------
__global__ __launch_bounds__(256) void gemm2_kernel(
    const float* __restrict__ h1,
    const float* __restrict__ W, const float* __restrict__ bias,
    float* __restrict__ y, float* __restrict__ stats)
{
    __shared__ float Wlds[64 * 128];
    __shared__ float hlds[32 * 128];

    const int tid = threadIdx.x;
    const int cg = tid & 31;
    const int rg = tid >> 5;
    const int c0 = cg * 4;
    const int rowBase = blockIdx.x * 32;

    for (int i = tid; i < 32 * 128 / 4; i += 256) {
        int row = i >> 5;
        int col = (i & 31) * 4;
        int r = rowBase + row;
        float4 v = make_float4(0.f, 0.f, 0.f, 0.f);
        if (r < N_NODES) {
            v = *(const float4*)&h1[r * 128 + col];
        }
        *(float4*)&hlds[i * 4] = v;
    }

    float acc[4][4] = {{0.f}};

    for (int kc = 0; kc < 2; ++kc) {
        __syncthreads();
        for (int i = tid; i < 64 * 128 / 4; i += 256) {
            *(float4*)&Wlds[i * 4] = *(const float4*)&W[kc * 64 * 128 + i * 4];
        }
        __syncthreads();
        #pragma unroll 16
        for (int k = 0; k < 64; ++k) {
            float4 w = *(float4*)&Wlds[k * 128 + c0];
            float h0 = hlds[(rg * 4 + 0) * 128 + kc * 64 + k];
            float h1v = hlds[(rg * 4 + 1) * 128 + kc * 64 + k];
            float h2 = hlds[(rg * 4 + 2) * 128 + kc * 64 + k];
            float h3 = hlds[(rg * 4 + 3) * 128 + kc * 64 + k];
            acc[0][0] += h0 * w.x;  acc[0][1] += h0 * w.y;  acc[0][2] += h0 * w.z;  acc[0][3] += h0 * w.w;
            acc[1][0] += h1v * w.x; acc[1][1] += h1v * w.y; acc[1][2] += h1v * w.z; acc[1][3] += h1v * w.w;
            acc[2][0] += h2 * w.x;  acc[2][1] += h2 * w.y;  acc[2][2] += h2 * w.z;  acc[2][3] += h2 * w.w;
            acc[3][0] += h3 * w.x;  acc[3][1] += h3 * w.y;  acc[3][2] += h3 * w.z;  acc[3][3] += h3 * w.w;
        }
    }

    float4 bv = *(const float4*)&bias[c0];
    float ps[4] = {0.f, 0.f, 0.f, 0.f};
    float pq[4] = {0.f, 0.f, 0.f, 0.f};
    #pragma unroll
    for (int j = 0; j < 4; ++j) {
        int r = rowBase + rg * 4 + j;
        if (r < N_NODES) {
            float4 o;
            o.x = fmaxf(acc[j][0] + bv.x, 0.f);
            o.y = fmaxf(acc[j][1] + bv.y, 0.f);
            o.z = fmaxf(acc[j][2] + bv.z, 0.f);
            o.w = fmaxf(acc[j][3] + bv.w, 0.f);
            *(float4*)&y[r * 128 + c0] = o;
            ps[0] += o.x; ps[1] += o.y; ps[2] += o.z; ps[3] += o.w;
            pq[0] += o.x * o.x; pq[1] += o.y * o.y; pq[2] += o.z * o.z; pq[3] += o.w * o.w;
        }
    }

    __syncthreads();
    float* sums = hlds;          // [8][128]
    float* sqs  = hlds + 1024;   // [8][128]
    *(float4*)&sums[rg * 128 + c0] = make_float4(ps[0], ps[1], ps[2], ps[3]);
    *(float4*)&sqs[rg * 128 + c0]  = make_float4(pq[0], pq[1], pq[2], pq[3]);
    __syncthreads();
    if (tid < 128) {
        float s = 0.f, q = 0.f;
        #pragma unroll
        for (int g = 0; g < 8; ++g) {
            s += sums[g * 128 + tid];
            q += sqs[g * 128 + tid];
        }
        atomicAdd(&stats[tid], s);
        atomicAdd(&stats[128 + tid], q);
    }
}

// ---------------------------------------------------------------------------
// BatchNorm apply, in place on y (= d_out)
// ---------------------------------------------------------------------------
__global__ void bn_kernel(float* __restrict__ y,
                          const float* __restrict__ stats,
                          const float* __restrict__ gamma,
                          const float* __restrict__ beta)
{
    int gid = blockIdx.x * blockDim.x + threadIdx.x;
    const int n4 = N_NODES * D / 4;
    if (gid >= n4) return;
    int c0 = (gid << 2) & 127;
    const float inv_n = 1.0f / (float)N_NODES;
    float4 v = ((float4*)y)[gid];
    float4 s = *(const float4*)&stats[c0];
    float4 q = *(const float4*)&stats[128 + c0];
    float4 g = *(const float4*)&gamma[c0];
    float4 b = *(const float4*)&beta[c0];

    float m, var;
    m = s.x * inv_n; var = q.x * inv_n - m * m;
    v.x = (v.x - m) * rsqrtf(var + BN_EPS) * g.x + b.x;
    m = s.y * inv_n; var = q.y * inv_n - m * m;
    v.y = (v.y - m) * rsqrtf(var + BN_EPS) * g.y + b.y;
    m = s.z * inv_n; var = q.z * inv_n - m * m;
    v.z = (v.z - m) * rsqrtf(var + BN_EPS) * g.z + b.z;
    m = s.w * inv_n; var = q.w * inv_n - m * m;
    v.w = (v.w - m) * rsqrtf(var + BN_EPS) * g.w + b.w;

    ((float4*)y)[gid] = v;
}

// ---------------------------------------------------------------------------
extern "C" void kernel_launch(void* const* d_in, const int* in_sizes, int n_in,
                              void* d_out, int out_size, void* d_ws, size_t ws_size,
                              hipStream_t stream) {
    const float* feature = (const float*)d_in[0];
    const int*   ei      = (const int*)d_in[1];
    const float* W1      = (const float*)d_in[2];
    const float* b1      = (const float*)d_in[3];
    const float* W2      = (const float*)d_in[4];
    const float* b2      = (const float*)d_in[5];
    const float* gamma   = (const float*)d_in[6];
    const float* beta    = (const float*)d_in[7];
    float* out = (float*)d_out;

    float* agg   = (float*)d_ws;            // 6,400,000 floats
    float* h1    = agg + N_NODES * D;       // 6,400,000 floats
    float* stats = h1 + N_NODES * D;        // 256 floats

    // Sort temporaries overlaid on the h1 region (only live before gemm1).
    int* cnt    = (int*)h1;                 // 50000
    int* offs   = cnt + N_NODES;            // 50001
    int* cursor = offs + N_NODES + 1;       // 50000
    int* ssrc   = cursor + N_NODES;         // 600000
    int* bsum   = ssrc + N_EDGES;           // SCAN_BLOCKS

    // 1. zero counts + stats
    zero_kernel<<<(N_NODES + 255) / 256, 256, 0, stream>>>(cnt, stats);
    // 2. histogram of dst
    hist_kernel<<<(N_EDGES + 255) / 256, 256, 0, stream>>>(ei, cnt);
    // 3. exclusive scan -> offs, cursor
    scanA_kernel<<<SCAN_BLOCKS, 1024, 0, stream>>>(cnt, offs, bsum);
    scanB_kernel<<<1, 64, 0, stream>>>(bsum);
    scanC_kernel<<<SCAN_BLOCKS, 1024, 0, stream>>>(offs, bsum, cursor);
    // 4. scatter src indices into dst-sorted order
    scatter_idx_kernel<<<(N_EDGES + 255) / 256, 256, 0, stream>>>(ei, cursor, ssrc);
    // 5. gather-sum neighbors
    gather_kernel<<<(N_NODES * 64 + 255) / 256, 256, 0, stream>>>(feature, offs, ssrc, agg);
    // 6. GEMM1 + ReLU
    gemm1_kernel<<<(N_NODES + 31) / 32, 256, 0, stream>>>(feature, agg, W1, b1, h1);
    // 7. GEMM2 + ReLU + BN stats
    gemm2_kernel<<<(N_NODES + 31) / 32, 256, 0, stream>>>(h1, W2, b2, out, stats);
    // 8. BN apply
    bn_kernel<<<(N_NODES * D / 4 + 255) / 256, 256, 0, stream>>>(out, stats, gamma, beta);
}

// Round 3
// 259.017 us; speedup vs baseline: 1.7324x; 1.2318x over previous
//
#include <hip/hip_runtime.h>

#define N_NODES 50000
#define D 128
#define N_EDGES 600000
#define BN_EPS 1e-5f
#define SCAN_BLOCKS 49  // ceil(50000/1024)

typedef __attribute__((ext_vector_type(8))) short short8;
typedef __attribute__((ext_vector_type(4))) float floatx4;

__device__ __forceinline__ unsigned f2bf(float f) {
    unsigned x = __float_as_uint(f);
    return (x + 0x7fffu + ((x >> 16) & 1u)) >> 16;  // RNE
}
__device__ __forceinline__ float bflo(unsigned v) { return __uint_as_float(v << 16); }
__device__ __forceinline__ float bfhi(unsigned v) { return __uint_as_float(v & 0xffff0000u); }

// ---------------------------------------------------------------------------
// Zero counts (50000 ints) and stats (256 floats)
// ---------------------------------------------------------------------------
__global__ void zero_kernel(int* __restrict__ cnt, float* __restrict__ stats) {
    int gid = blockIdx.x * blockDim.x + threadIdx.x;
    if (gid < N_NODES) cnt[gid] = 0;
    if (gid < 256) stats[gid] = 0.f;
}

// ---------------------------------------------------------------------------
// feature fp32 -> bf16 (packed), 8 elements/thread
// ---------------------------------------------------------------------------
__global__ void featconv_kernel(const float* __restrict__ f, unsigned* __restrict__ fb) {
    int gid = blockIdx.x * blockDim.x + threadIdx.x;  // 800000
    if (gid >= N_NODES * D / 8) return;
    float4 a = ((const float4*)f)[gid * 2];
    float4 b = ((const float4*)f)[gid * 2 + 1];
    uint4 o;
    o.x = f2bf(a.x) | (f2bf(a.y) << 16);
    o.y = f2bf(a.z) | (f2bf(a.w) << 16);
    o.z = f2bf(b.x) | (f2bf(b.y) << 16);
    o.w = f2bf(b.z) | (f2bf(b.w) << 16);
    ((uint4*)fb)[gid] = o;
}

// ---------------------------------------------------------------------------
// Weights: W[k][n] fp32 -> Wt[n][k] bf16, both W1 and W2
// ---------------------------------------------------------------------------
__global__ void wprep_kernel(const float* __restrict__ W1, const float* __restrict__ W2,
                             unsigned short* __restrict__ Wt1, unsigned short* __restrict__ Wt2) {
    int gid = blockIdx.x * blockDim.x + threadIdx.x;  // 32768
    if (gid >= 2 * D * D) return;
    int m = gid >> 14;
    int idx = gid & (D * D - 1);
    int k = idx >> 7;
    int n = idx & 127;
    const float* W = m ? W2 : W1;
    unsigned short* Wt = m ? Wt2 : Wt1;
    Wt[n * D + k] = (unsigned short)f2bf(W[k * D + n]);
}

// ---------------------------------------------------------------------------
// Histogram of dst
// ---------------------------------------------------------------------------
__global__ void hist_kernel(const int* __restrict__ ei, int* __restrict__ cnt) {
    int e = blockIdx.x * blockDim.x + threadIdx.x;
    if (e >= N_EDGES) return;
    atomicAdd(&cnt[ei[N_EDGES + e]], 1);
}

// ---------------------------------------------------------------------------
// Scan pass A/B/C: exclusive scan of cnt -> offs, plus cursor copy
// ---------------------------------------------------------------------------
__global__ __launch_bounds__(1024) void scanA_kernel(const int* __restrict__ cnt,
                                                     int* __restrict__ offs,
                                                     int* __restrict__ bsum) {
    __shared__ int buf[1024];
    int tid = threadIdx.x;
    int i = blockIdx.x * 1024 + tid;
    int v = (i < N_NODES) ? cnt[i] : 0;
    buf[tid] = v;
    __syncthreads();
    for (int off = 1; off < 1024; off <<= 1) {
        int t = (tid >= off) ? buf[tid - off] : 0;
        __syncthreads();
        buf[tid] += t;
        __syncthreads();
    }
    int incl = buf[tid];
    if (i < N_NODES) offs[i] = incl - v;
    if (tid == 1023) bsum[blockIdx.x] = incl;
}

__global__ void scanB_kernel(int* __restrict__ bsum) {
    if (threadIdx.x == 0 && blockIdx.x == 0) {
        int running = 0;
        for (int b = 0; b < SCAN_BLOCKS; ++b) {
            int t = bsum[b];
            bsum[b] = running;
            running += t;
        }
    }
}

__global__ __launch_bounds__(1024) void scanC_kernel(int* __restrict__ offs,
                                                     const int* __restrict__ bsum,
                                                     int* __restrict__ cursor) {
    int i = blockIdx.x * 1024 + threadIdx.x;
    if (i == 0) offs[N_NODES] = N_EDGES;
    if (i >= N_NODES) return;
    int v = offs[i] + bsum[i >> 10];
    offs[i] = v;
    cursor[i] = v;
}

// ---------------------------------------------------------------------------
// Scatter edge src indices into dst-sorted order
// ---------------------------------------------------------------------------
__global__ void scatter_idx_kernel(const int* __restrict__ ei,
                                   int* __restrict__ cursor,
                                   int* __restrict__ ssrc) {
    int e = blockIdx.x * blockDim.x + threadIdx.x;
    if (e >= N_EDGES) return;
    int src = ei[e];
    int dst = ei[N_EDGES + e];
    int pos = atomicAdd(&cursor[dst], 1);
    ssrc[pos] = src;
}

// ---------------------------------------------------------------------------
// Gather: h[n] = feat[n] + sum_{s in nbrs(n)} feat[s], all bf16 in / bf16 out,
// fp32 accumulate. One wave per node, lane handles 2 columns (one packed uint).
// ---------------------------------------------------------------------------
__global__ __launch_bounds__(256) void gather_kernel(const unsigned* __restrict__ fb,
                                                     const int* __restrict__ offs,
                                                     const int* __restrict__ ssrc,
                                                     unsigned* __restrict__ hb) {
    int node = (blockIdx.x * 256 + threadIdx.x) >> 6;
    int lane = threadIdx.x & 63;
    if (node >= N_NODES) return;
    int beg = offs[node];
    int end = offs[node + 1];
    float a0 = 0.f, a1 = 0.f;
    int j = beg;
    for (; j + 1 < end; j += 2) {
        int s0 = ssrc[j];
        int s1 = ssrc[j + 1];
        unsigned v0 = fb[s0 * 64 + lane];
        unsigned v1 = fb[s1 * 64 + lane];
        a0 += bflo(v0) + bflo(v1);
        a1 += bfhi(v0) + bfhi(v1);
    }
    if (j < end) {
        unsigned v = fb[ssrc[j] * 64 + lane];
        a0 += bflo(v);
        a1 += bfhi(v);
    }
    unsigned own = fb[node * 64 + lane];
    a0 += bflo(own);
    a1 += bfhi(own);
    hb[node * 64 + lane] = f2bf(a0) | (f2bf(a1) << 16);
}

// ---------------------------------------------------------------------------
// MFMA GEMM1: h1b = bf16(relu(hb @ W1 + b1))
// 64 rows/block, 4 waves x 16 rows, full N=128 per wave, K=128 in 4 chunks.
// A LDS [64][136] bf16, B LDS [128][136] bf16 (both +8 pad -> 2-way only).
// ---------------------------------------------------------------------------
__global__ __launch_bounds__(256) void gemm1_kernel(
    const unsigned short* __restrict__ A, const unsigned short* __restrict__ Bt,
    const float* __restrict__ bias, unsigned short* __restrict__ h1b)
{
    __shared__ unsigned short Albs[64 * 136];
    __shared__ unsigned short Blds[128 * 136];

    const int tid = threadIdx.x;
    const int rowBase = blockIdx.x * 64;

    #pragma unroll
    for (int i = 0; i < 4; ++i) {  // A: 1024 16B chunks
        int c = tid + i * 256;
        int row = c >> 4;
        int off8 = (c & 15) * 8;
        uint4 v = make_uint4(0, 0, 0, 0);
        if (rowBase + row < N_NODES)
            v = *(const uint4*)&A[(rowBase + row) * 128 + off8];
        *(uint4*)&Albs[row * 136 + off8] = v;
    }
    #pragma unroll
    for (int i = 0; i < 8; ++i) {  // B: 2048 16B chunks
        int c = tid + i * 256;
        int row = c >> 4;
        int off8 = (c & 15) * 8;
        *(uint4*)&Blds[row * 136 + off8] = *(const uint4*)&Bt[row * 128 + off8];
    }
    __syncthreads();

    const int lane = tid & 63;
    const int wid = tid >> 6;
    const unsigned short* Ab = &Albs[(wid * 16 + (lane & 15)) * 136 + (lane >> 4) * 8];
    const unsigned short* Bb = &Blds[(lane & 15) * 136 + (lane >> 4) * 8];

    floatx4 acc[8];
    #pragma unroll
    for (int n = 0; n < 8; ++n) acc[n] = (floatx4){0.f, 0.f, 0.f, 0.f};

    #pragma unroll
    for (int kc = 0; kc < 4; ++kc) {
        short8 af = *(const short8*)(Ab + kc * 32);
        #pragma unroll
        for (int n = 0; n < 8; ++n) {
            short8 bf = *(const short8*)(Bb + n * 16 * 136 + kc * 32);
            acc[n] = __builtin_amdgcn_mfma_f32_16x16x32_bf16(af, bf, acc[n], 0, 0, 0);
        }
    }

    int r0 = rowBase + wid * 16 + (lane >> 4) * 4;
    int col0 = lane & 15;
    #pragma unroll
    for (int n = 0; n < 8; ++n) {
        int col = n * 16 + col0;
        float b = bias[col];
        #pragma unroll
        for (int r = 0; r < 4; ++r) {
            int row = r0 + r;
            if (row < N_NODES) {
                float v = fmaxf(acc[n][r] + b, 0.f);
                h1b[row * 128 + col] = (unsigned short)f2bf(v);
            }
        }
    }
}

// ---------------------------------------------------------------------------
// MFMA GEMM2: y = relu(h1b @ W2 + b2) fp32 to out, + BN column sum/sumsq.
// ---------------------------------------------------------------------------
__global__ __launch_bounds__(256) void gemm2_kernel(
    const unsigned short* __restrict__ A, const unsigned short* __restrict__ Bt,
    const float* __restrict__ bias, float* __restrict__ out, float* __restrict__ stats)
{
    __shared__ unsigned short Albs[64 * 136];
    __shared__ unsigned short Blds[128 * 136];

    const int tid = threadIdx.x;
    const int rowBase = blockIdx.x * 64;

    #pragma unroll
    for (int i = 0; i < 4; ++i) {
        int c = tid + i * 256;
        int row = c >> 4;
        int off8 = (c & 15) * 8;
        uint4 v = make_uint4(0, 0, 0, 0);
        if (rowBase + row < N_NODES)
            v = *(const uint4*)&A[(rowBase + row) * 128 + off8];
        *(uint4*)&Albs[row * 136 + off8] = v;
    }
    #pragma unroll
    for (int i = 0; i < 8; ++i) {
        int c = tid + i * 256;
        int row = c >> 4;
        int off8 = (c & 15) * 8;
        *(uint4*)&Blds[row * 136 + off8] = *(const uint4*)&Bt[row * 128 + off8];
    }
    __syncthreads();

    const int lane = tid & 63;
    const int wid = tid >> 6;
    const unsigned short* Ab = &Albs[(wid * 16 + (lane & 15)) * 136 + (lane >> 4) * 8];
    const unsigned short* Bb = &Blds[(lane & 15) * 136 + (lane >> 4) * 8];

    floatx4 acc[8];
    #pragma unroll
    for (int n = 0; n < 8; ++n) acc[n] = (floatx4){0.f, 0.f, 0.f, 0.f};

    #pragma unroll
    for (int kc = 0; kc < 4; ++kc) {
        short8 af = *(const short8*)(Ab + kc * 32);
        #pragma unroll
        for (int n = 0; n < 8; ++n) {
            short8 bf = *(const short8*)(Bb + n * 16 * 136 + kc * 32);
            acc[n] = __builtin_amdgcn_mfma_f32_16x16x32_bf16(af, bf, acc[n], 0, 0, 0);
        }
    }

    int r0 = rowBase + wid * 16 + (lane >> 4) * 4;
    int col0 = lane & 15;
    float s[8], q[8];
    #pragma unroll
    for (int n = 0; n < 8; ++n) {
        s[n] = 0.f; q[n] = 0.f;
        int col = n * 16 + col0;
        float b = bias[col];
        #pragma unroll
        for (int r = 0; r < 4; ++r) {
            int row = r0 + r;
            if (row < N_NODES) {
                float v = fmaxf(acc[n][r] + b, 0.f);
                out[row * 128 + col] = v;
                s[n] += v;
                q[n] += v * v;
            }
        }
    }

    // reduce across the 4 quads (rows) -> lanes 0..15 hold 16-row col sums
    #pragma unroll
    for (int n = 0; n < 8; ++n) {
        s[n] += __shfl_xor(s[n], 16);
        s[n] += __shfl_xor(s[n], 32);
        q[n] += __shfl_xor(q[n], 16);
        q[n] += __shfl_xor(q[n], 32);
    }
    __syncthreads();  // done reading LDS; reuse Albs as reduction scratch
    float* red = (float*)Albs;  // [0..511]=sums [512..1023]=sqs
    if (lane < 16) {
        #pragma unroll
        for (int n = 0; n < 8; ++n) {
            red[wid * 128 + n * 16 + lane] = s[n];
            red[512 + wid * 128 + n * 16 + lane] = q[n];
        }
    }
    __syncthreads();
    if (tid < 128) {
        float ss = 0.f, qq = 0.f;
        #pragma unroll
        for (int w = 0; w < 4; ++w) {
            ss += red[w * 128 + tid];
            qq += red[512 + w * 128 + tid];
        }
        atomicAdd(&stats[tid], ss);
        atomicAdd(&stats[128 + tid], qq);
    }
}

// ---------------------------------------------------------------------------
// BatchNorm apply, in place on out
// ---------------------------------------------------------------------------
__global__ void bn_kernel(float* __restrict__ y,
                          const float* __restrict__ stats,
                          const float* __restrict__ gamma,
                          const float* __restrict__ beta)
{
    int gid = blockIdx.x * blockDim.x + threadIdx.x;
    const int n4 = N_NODES * D / 4;
    if (gid >= n4) return;
    int c0 = (gid << 2) & 127;
    const float inv_n = 1.0f / (float)N_NODES;
    float4 v = ((float4*)y)[gid];
    float4 s = *(const float4*)&stats[c0];
    float4 q = *(const float4*)&stats[128 + c0];
    float4 g = *(const float4*)&gamma[c0];
    float4 b = *(const float4*)&beta[c0];

    float m, var;
    m = s.x * inv_n; var = q.x * inv_n - m * m;
    v.x = (v.x - m) * rsqrtf(var + BN_EPS) * g.x + b.x;
    m = s.y * inv_n; var = q.y * inv_n - m * m;
    v.y = (v.y - m) * rsqrtf(var + BN_EPS) * g.y + b.y;
    m = s.z * inv_n; var = q.z * inv_n - m * m;
    v.z = (v.z - m) * rsqrtf(var + BN_EPS) * g.z + b.z;
    m = s.w * inv_n; var = q.w * inv_n - m * m;
    v.w = (v.w - m) * rsqrtf(var + BN_EPS) * g.w + b.w;

    ((float4*)y)[gid] = v;
}

// ---------------------------------------------------------------------------
extern "C" void kernel_launch(void* const* d_in, const int* in_sizes, int n_in,
                              void* d_out, int out_size, void* d_ws, size_t ws_size,
                              hipStream_t stream) {
    const float* feature = (const float*)d_in[0];
    const int*   ei      = (const int*)d_in[1];
    const float* W1      = (const float*)d_in[2];
    const float* b1      = (const float*)d_in[3];
    const float* W2      = (const float*)d_in[4];
    const float* b2      = (const float*)d_in[5];
    const float* gamma   = (const float*)d_in[6];
    const float* beta    = (const float*)d_in[7];
    float* out = (float*)d_out;

    // ws layout (bytes):
    unsigned*       featb = (unsigned*)d_ws;                       // 50000*64 uints = 12.8 MB
    unsigned*       hb    = featb + N_NODES * 64;                  // 12.8 MB
    unsigned short* h1b   = (unsigned short*)(hb + N_NODES * 64);  // 12.8 MB
    unsigned short* Wt1   = h1b + N_NODES * D;                     // 32 KB
    unsigned short* Wt2   = Wt1 + D * D;                           // 32 KB
    float*          stats = (float*)(Wt2 + D * D);                 // 1 KB
    int*            cnt   = (int*)(stats + 256);                   // 50000
    int*            offs  = cnt + N_NODES;                         // 50001
    int*            cursor= offs + N_NODES + 1;                    // 50000
    int*            ssrc  = cursor + N_NODES;                      // 600000
    int*            bsum  = ssrc + N_EDGES;                        // SCAN_BLOCKS

    zero_kernel<<<(N_NODES + 255) / 256, 256, 0, stream>>>(cnt, stats);
    featconv_kernel<<<(N_NODES * D / 8 + 255) / 256, 256, 0, stream>>>(feature, featb);
    wprep_kernel<<<(2 * D * D + 255) / 256, 256, 0, stream>>>(W1, W2, Wt1, Wt2);
    hist_kernel<<<(N_EDGES + 255) / 256, 256, 0, stream>>>(ei, cnt);
    scanA_kernel<<<SCAN_BLOCKS, 1024, 0, stream>>>(cnt, offs, bsum);
    scanB_kernel<<<1, 64, 0, stream>>>(bsum);
    scanC_kernel<<<SCAN_BLOCKS, 1024, 0, stream>>>(offs, bsum, cursor);
    scatter_idx_kernel<<<(N_EDGES + 255) / 256, 256, 0, stream>>>(ei, cursor, ssrc);
    gather_kernel<<<N_NODES * 64 / 256, 256, 0, stream>>>(featb, offs, ssrc, hb);
    gemm1_kernel<<<(N_NODES + 63) / 64, 256, 0, stream>>>((const unsigned short*)hb, Wt1, b1, h1b);
    gemm2_kernel<<<(N_NODES + 63) / 64, 256, 0, stream>>>(h1b, Wt2, b2, out, stats);
    bn_kernel<<<(N_NODES * D / 4 + 255) / 256, 256, 0, stream>>>(out, stats, gamma, beta);
}

// Round 4
// 240.149 us; speedup vs baseline: 1.8685x; 1.0786x over previous
//
#include <hip/hip_runtime.h>

#define N_NODES 50000
#define D 128
#define N_EDGES 600000
#define BN_EPS 1e-5f
#define SCAN_BLOCKS 49  // ceil(50000/1024)

// prep_kernel block ranges
#define FEATC_BLOCKS 3125   // 800000 / 256
#define WPREP_BLOCKS 128    // 32768 / 256
#define ZERO_BLOCKS  197    // ceil(50432/256)

typedef __attribute__((ext_vector_type(8))) short short8;
typedef __attribute__((ext_vector_type(4))) float floatx4;

__device__ __forceinline__ unsigned f2bf(float f) {
    unsigned x = __float_as_uint(f);
    return (x + 0x7fffu + ((x >> 16) & 1u)) >> 16;  // RNE
}
__device__ __forceinline__ float bflo(unsigned v) { return __uint_as_float(v << 16); }
__device__ __forceinline__ float bfhi(unsigned v) { return __uint_as_float(v & 0xffff0000u); }

// ---------------------------------------------------------------------------
// Fused prep: featconv (fp32->bf16), weight transpose+convert, zero cnt/stats
// ---------------------------------------------------------------------------
__global__ void prep_kernel(const float* __restrict__ f, unsigned* __restrict__ fb,
                            const float* __restrict__ W1, const float* __restrict__ W2,
                            unsigned short* __restrict__ Wt1, unsigned short* __restrict__ Wt2,
                            int* __restrict__ cnt, float* __restrict__ stats) {
    int b = blockIdx.x;
    int tid = threadIdx.x;
    if (b < FEATC_BLOCKS) {
        int gid = b * 256 + tid;  // < 800000 exactly
        float4 a = ((const float4*)f)[gid * 2];
        float4 c = ((const float4*)f)[gid * 2 + 1];
        uint4 o;
        o.x = f2bf(a.x) | (f2bf(a.y) << 16);
        o.y = f2bf(a.z) | (f2bf(a.w) << 16);
        o.z = f2bf(c.x) | (f2bf(c.y) << 16);
        o.w = f2bf(c.z) | (f2bf(c.w) << 16);
        ((uint4*)fb)[gid] = o;
    } else if (b < FEATC_BLOCKS + WPREP_BLOCKS) {
        int gid = (b - FEATC_BLOCKS) * 256 + tid;  // < 32768
        int m = gid >> 14;
        int idx = gid & (D * D - 1);
        int k = idx >> 7;
        int n = idx & 127;
        const float* W = m ? W2 : W1;
        unsigned short* Wt = m ? Wt2 : Wt1;
        Wt[n * D + k] = (unsigned short)f2bf(W[k * D + n]);
    } else {
        int gid = (b - FEATC_BLOCKS - WPREP_BLOCKS) * 256 + tid;
        if (gid < N_NODES) cnt[gid] = 0;
        if (gid < 256) stats[gid] = 0.f;
    }
}

// ---------------------------------------------------------------------------
// Histogram of dst
// ---------------------------------------------------------------------------
__global__ void hist_kernel(const int* __restrict__ ei, int* __restrict__ cnt) {
    int e = blockIdx.x * blockDim.x + threadIdx.x;
    if (e >= N_EDGES) return;
    atomicAdd(&cnt[ei[N_EDGES + e]], 1);
}

// ---------------------------------------------------------------------------
// Scan A/B/C: exclusive scan of cnt -> offs, plus cursor copy
// ---------------------------------------------------------------------------
__global__ __launch_bounds__(1024) void scanA_kernel(const int* __restrict__ cnt,
                                                     int* __restrict__ offs,
                                                     int* __restrict__ bsum) {
    __shared__ int buf[1024];
    int tid = threadIdx.x;
    int i = blockIdx.x * 1024 + tid;
    int v = (i < N_NODES) ? cnt[i] : 0;
    buf[tid] = v;
    __syncthreads();
    for (int off = 1; off < 1024; off <<= 1) {
        int t = (tid >= off) ? buf[tid - off] : 0;
        __syncthreads();
        buf[tid] += t;
        __syncthreads();
    }
    int incl = buf[tid];
    if (i < N_NODES) offs[i] = incl - v;
    if (tid == 1023) bsum[blockIdx.x] = incl;
}

__global__ void scanB_kernel(int* __restrict__ bsum) {
    if (threadIdx.x == 0 && blockIdx.x == 0) {
        int running = 0;
        for (int b = 0; b < SCAN_BLOCKS; ++b) {
            int t = bsum[b];
            bsum[b] = running;
            running += t;
        }
    }
}

__global__ __launch_bounds__(1024) void scanC_kernel(int* __restrict__ offs,
                                                     const int* __restrict__ bsum,
                                                     int* __restrict__ cursor) {
    int i = blockIdx.x * 1024 + threadIdx.x;
    if (i == 0) offs[N_NODES] = N_EDGES;
    if (i >= N_NODES) return;
    int v = offs[i] + bsum[i >> 10];
    offs[i] = v;
    cursor[i] = v;
}

// ---------------------------------------------------------------------------
// Scatter edge src indices into dst-sorted order
// ---------------------------------------------------------------------------
__global__ void scatter_idx_kernel(const int* __restrict__ ei,
                                   int* __restrict__ cursor,
                                   int* __restrict__ ssrc) {
    int e = blockIdx.x * blockDim.x + threadIdx.x;
    if (e >= N_EDGES) return;
    int src = ei[e];
    int dst = ei[N_EDGES + e];
    int pos = atomicAdd(&cursor[dst], 1);
    ssrc[pos] = src;
}

// ---------------------------------------------------------------------------
// Gather: h[n] = feat[n] + sum_{s in nbrs(n)} feat[s].
// 4 nodes per wave, 16 lanes per node, uint4 (8 bf16 = 16B) per lane.
// ---------------------------------------------------------------------------
__global__ __launch_bounds__(256) void gather_kernel(const uint4* __restrict__ fb4,
                                                     const int* __restrict__ offs,
                                                     const int* __restrict__ ssrc,
                                                     uint4* __restrict__ hb4) {
    int wave = (blockIdx.x * 256 + threadIdx.x) >> 6;
    int lane = threadIdx.x & 63;
    int quad = lane >> 4;
    int l16 = lane & 15;
    int node = wave * 4 + quad;   // 12500 waves * 4 = 50000 exactly
    int beg = offs[node];
    int end = offs[node + 1];

    float a0, a1, a2, a3, a4, a5, a6, a7;
    uint4 own = fb4[node * 16 + l16];
    a0 = bflo(own.x); a1 = bfhi(own.x);
    a2 = bflo(own.y); a3 = bfhi(own.y);
    a4 = bflo(own.z); a5 = bfhi(own.z);
    a6 = bflo(own.w); a7 = bfhi(own.w);

    int j = beg;
    for (; j + 1 < end; j += 2) {
        int s0 = ssrc[j];
        int s1 = ssrc[j + 1];
        uint4 v0 = fb4[s0 * 16 + l16];
        uint4 v1 = fb4[s1 * 16 + l16];
        a0 += bflo(v0.x) + bflo(v1.x); a1 += bfhi(v0.x) + bfhi(v1.x);
        a2 += bflo(v0.y) + bflo(v1.y); a3 += bfhi(v0.y) + bfhi(v1.y);
        a4 += bflo(v0.z) + bflo(v1.z); a5 += bfhi(v0.z) + bfhi(v1.z);
        a6 += bflo(v0.w) + bflo(v1.w); a7 += bfhi(v0.w) + bfhi(v1.w);
    }
    if (j < end) {
        uint4 v = fb4[ssrc[j] * 16 + l16];
        a0 += bflo(v.x); a1 += bfhi(v.x);
        a2 += bflo(v.y); a3 += bfhi(v.y);
        a4 += bflo(v.z); a5 += bfhi(v.z);
        a6 += bflo(v.w); a7 += bfhi(v.w);
    }

    uint4 o;
    o.x = f2bf(a0) | (f2bf(a1) << 16);
    o.y = f2bf(a2) | (f2bf(a3) << 16);
    o.z = f2bf(a4) | (f2bf(a5) << 16);
    o.w = f2bf(a6) | (f2bf(a7) << 16);
    hb4[node * 16 + l16] = o;
}

// ---------------------------------------------------------------------------
// MFMA GEMM1: h1b = bf16(relu(hb @ W1 + b1))
// 64 rows/block, 4 waves x 16 rows, N=128 per wave, K=128 in 4 chunks.
// LDS XOR-swizzled: granule (16B) g stored at g ^ (row & 15). Stride 128, no
// pad: fragment reads hit 16 distinct granules per quad -> 2-way max (free).
// ---------------------------------------------------------------------------
__global__ __launch_bounds__(256) void gemm1_kernel(
    const unsigned short* __restrict__ A, const unsigned short* __restrict__ Bt,
    const float* __restrict__ bias, unsigned short* __restrict__ h1b)
{
    __shared__ unsigned short Albs[64 * 128];
    __shared__ unsigned short Blds[128 * 128];

    const int tid = threadIdx.x;
    const int rowBase = blockIdx.x * 64;

    #pragma unroll
    for (int i = 0; i < 4; ++i) {  // A: 1024 16B granules
        int c = tid + i * 256;
        int row = c >> 4;
        int g = c & 15;
        uint4 v = make_uint4(0, 0, 0, 0);
        if (rowBase + row < N_NODES)
            v = *(const uint4*)&A[(rowBase + row) * 128 + g * 8];
        *(uint4*)&Albs[row * 128 + (g ^ (row & 15)) * 8] = v;
    }
    #pragma unroll
    for (int i = 0; i < 8; ++i) {  // B: 2048 16B granules
        int c = tid + i * 256;
        int row = c >> 4;
        int g = c & 15;
        *(uint4*)&Blds[row * 128 + (g ^ (row & 15)) * 8] =
            *(const uint4*)&Bt[row * 128 + g * 8];
    }
    __syncthreads();

    const int lane = tid & 63;
    const int wid = tid >> 6;
    const int l15 = lane & 15;
    const int quad = lane >> 4;
    const int arow = wid * 16 + l15;

    floatx4 acc[8];
    #pragma unroll
    for (int n = 0; n < 8; ++n) acc[n] = (floatx4){0.f, 0.f, 0.f, 0.f};

    #pragma unroll
    for (int kc = 0; kc < 4; ++kc) {
        int ga = (kc * 4 + quad) ^ l15;  // same for A and B (row&15 == l15)
        short8 af = *(const short8*)&Albs[arow * 128 + ga * 8];
        #pragma unroll
        for (int n = 0; n < 8; ++n) {
            short8 bf = *(const short8*)&Blds[(n * 16 + l15) * 128 + ga * 8];
            acc[n] = __builtin_amdgcn_mfma_f32_16x16x32_bf16(af, bf, acc[n], 0, 0, 0);
        }
    }

    int r0 = rowBase + wid * 16 + quad * 4;
    #pragma unroll
    for (int n = 0; n < 8; ++n) {
        int col = n * 16 + l15;
        float b = bias[col];
        #pragma unroll
        for (int r = 0; r < 4; ++r) {
            int row = r0 + r;
            if (row < N_NODES) {
                float v = fmaxf(acc[n][r] + b, 0.f);
                h1b[row * 128 + col] = (unsigned short)f2bf(v);
            }
        }
    }
}

// ---------------------------------------------------------------------------
// MFMA GEMM2: y = relu(h1b @ W2 + b2) fp32 to out, + BN column sum/sumsq.
// ---------------------------------------------------------------------------
__global__ __launch_bounds__(256) void gemm2_kernel(
    const unsigned short* __restrict__ A, const unsigned short* __restrict__ Bt,
    const float* __restrict__ bias, float* __restrict__ out, float* __restrict__ stats)
{
    __shared__ unsigned short Albs[64 * 128];
    __shared__ unsigned short Blds[128 * 128];

    const int tid = threadIdx.x;
    const int rowBase = blockIdx.x * 64;

    #pragma unroll
    for (int i = 0; i < 4; ++i) {
        int c = tid + i * 256;
        int row = c >> 4;
        int g = c & 15;
        uint4 v = make_uint4(0, 0, 0, 0);
        if (rowBase + row < N_NODES)
            v = *(const uint4*)&A[(rowBase + row) * 128 + g * 8];
        *(uint4*)&Albs[row * 128 + (g ^ (row & 15)) * 8] = v;
    }
    #pragma unroll
    for (int i = 0; i < 8; ++i) {
        int c = tid + i * 256;
        int row = c >> 4;
        int g = c & 15;
        *(uint4*)&Blds[row * 128 + (g ^ (row & 15)) * 8] =
            *(const uint4*)&Bt[row * 128 + g * 8];
    }
    __syncthreads();

    const int lane = tid & 63;
    const int wid = tid >> 6;
    const int l15 = lane & 15;
    const int quad = lane >> 4;
    const int arow = wid * 16 + l15;

    floatx4 acc[8];
    #pragma unroll
    for (int n = 0; n < 8; ++n) acc[n] = (floatx4){0.f, 0.f, 0.f, 0.f};

    #pragma unroll
    for (int kc = 0; kc < 4; ++kc) {
        int ga = (kc * 4 + quad) ^ l15;
        short8 af = *(const short8*)&Albs[arow * 128 + ga * 8];
        #pragma unroll
        for (int n = 0; n < 8; ++n) {
            short8 bf = *(const short8*)&Blds[(n * 16 + l15) * 128 + ga * 8];
            acc[n] = __builtin_amdgcn_mfma_f32_16x16x32_bf16(af, bf, acc[n], 0, 0, 0);
        }
    }

    int r0 = rowBase + wid * 16 + quad * 4;
    float s[8], q[8];
    #pragma unroll
    for (int n = 0; n < 8; ++n) {
        s[n] = 0.f; q[n] = 0.f;
        int col = n * 16 + l15;
        float b = bias[col];
        #pragma unroll
        for (int r = 0; r < 4; ++r) {
            int row = r0 + r;
            if (row < N_NODES) {
                float v = fmaxf(acc[n][r] + b, 0.f);
                out[row * 128 + col] = v;
                s[n] += v;
                q[n] += v * v;
            }
        }
    }

    #pragma unroll
    for (int n = 0; n < 8; ++n) {
        s[n] += __shfl_xor(s[n], 16);
        s[n] += __shfl_xor(s[n], 32);
        q[n] += __shfl_xor(q[n], 16);
        q[n] += __shfl_xor(q[n], 32);
    }
    __syncthreads();
    float* red = (float*)Albs;  // [0..511]=sums [512..1023]=sqs
    if (lane < 16) {
        #pragma unroll
        for (int n = 0; n < 8; ++n) {
            red[wid * 128 + n * 16 + lane] = s[n];
            red[512 + wid * 128 + n * 16 + lane] = q[n];
        }
    }
    __syncthreads();
    if (tid < 128) {
        float ss = 0.f, qq = 0.f;
        #pragma unroll
        for (int w = 0; w < 4; ++w) {
            ss += red[w * 128 + tid];
            qq += red[512 + w * 128 + tid];
        }
        atomicAdd(&stats[tid], ss);
        atomicAdd(&stats[128 + tid], qq);
    }
}

// ---------------------------------------------------------------------------
// BatchNorm apply, in place on out
// ---------------------------------------------------------------------------
__global__ void bn_kernel(float* __restrict__ y,
                          const float* __restrict__ stats,
                          const float* __restrict__ gamma,
                          const float* __restrict__ beta)
{
    int gid = blockIdx.x * blockDim.x + threadIdx.x;
    const int n4 = N_NODES * D / 4;
    if (gid >= n4) return;
    int c0 = (gid << 2) & 127;
    const float inv_n = 1.0f / (float)N_NODES;
    float4 v = ((float4*)y)[gid];
    float4 s = *(const float4*)&stats[c0];
    float4 q = *(const float4*)&stats[128 + c0];
    float4 g = *(const float4*)&gamma[c0];
    float4 b = *(const float4*)&beta[c0];

    float m, var;
    m = s.x * inv_n; var = q.x * inv_n - m * m;
    v.x = (v.x - m) * rsqrtf(var + BN_EPS) * g.x + b.x;
    m = s.y * inv_n; var = q.y * inv_n - m * m;
    v.y = (v.y - m) * rsqrtf(var + BN_EPS) * g.y + b.y;
    m = s.z * inv_n; var = q.z * inv_n - m * m;
    v.z = (v.z - m) * rsqrtf(var + BN_EPS) * g.z + b.z;
    m = s.w * inv_n; var = q.w * inv_n - m * m;
    v.w = (v.w - m) * rsqrtf(var + BN_EPS) * g.w + b.w;

    ((float4*)y)[gid] = v;
}

// ---------------------------------------------------------------------------
extern "C" void kernel_launch(void* const* d_in, const int* in_sizes, int n_in,
                              void* d_out, int out_size, void* d_ws, size_t ws_size,
                              hipStream_t stream) {
    const float* feature = (const float*)d_in[0];
    const int*   ei      = (const int*)d_in[1];
    const float* W1      = (const float*)d_in[2];
    const float* b1      = (const float*)d_in[3];
    const float* W2      = (const float*)d_in[4];
    const float* b2      = (const float*)d_in[5];
    const float* gamma   = (const float*)d_in[6];
    const float* beta    = (const float*)d_in[7];
    float* out = (float*)d_out;

    unsigned*       featb = (unsigned*)d_ws;                       // 12.8 MB
    unsigned*       hb    = featb + N_NODES * 64;                  // 12.8 MB
    unsigned short* h1b   = (unsigned short*)(hb + N_NODES * 64);  // 12.8 MB
    unsigned short* Wt1   = h1b + N_NODES * D;                     // 32 KB
    unsigned short* Wt2   = Wt1 + D * D;                           // 32 KB
    float*          stats = (float*)(Wt2 + D * D);                 // 1 KB
    int*            cnt   = (int*)(stats + 256);                   // 50000
    int*            offs  = cnt + N_NODES;                         // 50001
    int*            cursor= offs + N_NODES + 1;                    // 50000
    int*            ssrc  = cursor + N_NODES;                      // 600000
    int*            bsum  = ssrc + N_EDGES;                        // SCAN_BLOCKS

    prep_kernel<<<FEATC_BLOCKS + WPREP_BLOCKS + ZERO_BLOCKS, 256, 0, stream>>>(
        feature, featb, W1, W2, Wt1, Wt2, cnt, stats);
    hist_kernel<<<(N_EDGES + 255) / 256, 256, 0, stream>>>(ei, cnt);
    scanA_kernel<<<SCAN_BLOCKS, 1024, 0, stream>>>(cnt, offs, bsum);
    scanB_kernel<<<1, 64, 0, stream>>>(bsum);
    scanC_kernel<<<SCAN_BLOCKS, 1024, 0, stream>>>(offs, bsum, cursor);
    scatter_idx_kernel<<<(N_EDGES + 255) / 256, 256, 0, stream>>>(ei, cursor, ssrc);
    gather_kernel<<<N_NODES / 4 * 64 / 256, 256, 0, stream>>>(
        (const uint4*)featb, offs, ssrc, (uint4*)hb);
    gemm1_kernel<<<(N_NODES + 63) / 64, 256, 0, stream>>>((const unsigned short*)hb, Wt1, b1, h1b);
    gemm2_kernel<<<(N_NODES + 63) / 64, 256, 0, stream>>>(h1b, Wt2, b2, out, stats);
    bn_kernel<<<(N_NODES * D / 4 + 255) / 256, 256, 0, stream>>>(out, stats, gamma, beta);
}

// Round 5
// 220.818 us; speedup vs baseline: 2.0321x; 1.0875x over previous
//
#include <hip/hip_runtime.h>

#define N_NODES 50000
#define D 128
#define N_EDGES 600000
#define BN_EPS 1e-5f
#define SCAN_BLOCKS 49  // ceil(50000/1024)

// prep_kernel block ranges
#define FEATC_BLOCKS 3125   // 800000 / 256
#define WPREP_BLOCKS 128    // 32768 / 256
#define ZERO_BLOCKS  197    // ceil(50432/256)

typedef __attribute__((ext_vector_type(8))) short short8;
typedef __attribute__((ext_vector_type(4))) float floatx4;

__device__ __forceinline__ unsigned f2bf(float f) {
    unsigned x = __float_as_uint(f);
    return (x + 0x7fffu + ((x >> 16) & 1u)) >> 16;  // RNE
}
__device__ __forceinline__ float bflo(unsigned v) { return __uint_as_float(v << 16); }
__device__ __forceinline__ float bfhi(unsigned v) { return __uint_as_float(v & 0xffff0000u); }

// ---------------------------------------------------------------------------
// Fused prep: featconv (fp32->bf16), weight transpose+convert, zero cnt/stats
// ---------------------------------------------------------------------------
__global__ void prep_kernel(const float* __restrict__ f, unsigned* __restrict__ fb,
                            const float* __restrict__ W1, const float* __restrict__ W2,
                            unsigned short* __restrict__ Wt1, unsigned short* __restrict__ Wt2,
                            int* __restrict__ cnt, float* __restrict__ stats) {
    int b = blockIdx.x;
    int tid = threadIdx.x;
    if (b < FEATC_BLOCKS) {
        int gid = b * 256 + tid;  // < 800000 exactly
        float4 a = ((const float4*)f)[gid * 2];
        float4 c = ((const float4*)f)[gid * 2 + 1];
        uint4 o;
        o.x = f2bf(a.x) | (f2bf(a.y) << 16);
        o.y = f2bf(a.z) | (f2bf(a.w) << 16);
        o.z = f2bf(c.x) | (f2bf(c.y) << 16);
        o.w = f2bf(c.z) | (f2bf(c.w) << 16);
        ((uint4*)fb)[gid] = o;
    } else if (b < FEATC_BLOCKS + WPREP_BLOCKS) {
        int gid = (b - FEATC_BLOCKS) * 256 + tid;  // < 32768
        int m = gid >> 14;
        int idx = gid & (D * D - 1);
        int k = idx >> 7;
        int n = idx & 127;
        const float* W = m ? W2 : W1;
        unsigned short* Wt = m ? Wt2 : Wt1;
        Wt[n * D + k] = (unsigned short)f2bf(W[k * D + n]);
    } else {
        int gid = (b - FEATC_BLOCKS - WPREP_BLOCKS) * 256 + tid;
        if (gid < N_NODES) cnt[gid] = 0;
        if (gid < 256) stats[gid] = 0.f;
    }
}

// ---------------------------------------------------------------------------
// Histogram of dst
// ---------------------------------------------------------------------------
__global__ void hist_kernel(const int* __restrict__ ei, int* __restrict__ cnt) {
    int e = blockIdx.x * blockDim.x + threadIdx.x;
    if (e >= N_EDGES) return;
    atomicAdd(&cnt[ei[N_EDGES + e]], 1);
}

// ---------------------------------------------------------------------------
// Scan A: per-block (1024 elems) exclusive scan + block sums
// ---------------------------------------------------------------------------
__global__ __launch_bounds__(1024) void scanA_kernel(const int* __restrict__ cnt,
                                                     int* __restrict__ offs,
                                                     int* __restrict__ bsum) {
    __shared__ int buf[1024];
    int tid = threadIdx.x;
    int i = blockIdx.x * 1024 + tid;
    int v = (i < N_NODES) ? cnt[i] : 0;
    buf[tid] = v;
    __syncthreads();
    for (int off = 1; off < 1024; off <<= 1) {
        int t = (tid >= off) ? buf[tid - off] : 0;
        __syncthreads();
        buf[tid] += t;
        __syncthreads();
    }
    int incl = buf[tid];
    if (i < N_NODES) offs[i] = incl - v;
    if (tid == 1023) bsum[blockIdx.x] = incl;
}

// ---------------------------------------------------------------------------
// Scan C: each block computes its own prefix of bsum (49 values) with one
// wave-load + shfl reduction, then finalizes offs + cursor.
// ---------------------------------------------------------------------------
__global__ __launch_bounds__(1024) void scanC_kernel(int* __restrict__ offs,
                                                     const int* __restrict__ bsum,
                                                     int* __restrict__ cursor) {
    __shared__ int base_s;
    int tid = threadIdx.x;
    if (tid < 64) {
        int v = (tid < blockIdx.x) ? bsum[tid] : 0;  // blockIdx.x <= 48
        #pragma unroll
        for (int m = 32; m >= 1; m >>= 1) v += __shfl_xor(v, m);
        if (tid == 0) base_s = v;
    }
    __syncthreads();
    int i = blockIdx.x * 1024 + tid;
    if (i == 0) offs[N_NODES] = N_EDGES;
    if (i >= N_NODES) return;
    int v = offs[i] + base_s;
    offs[i] = v;
    cursor[i] = v;
}

// ---------------------------------------------------------------------------
// Scatter edge src indices into dst-sorted order
// ---------------------------------------------------------------------------
__global__ void scatter_idx_kernel(const int* __restrict__ ei,
                                   int* __restrict__ cursor,
                                   int* __restrict__ ssrc) {
    int e = blockIdx.x * blockDim.x + threadIdx.x;
    if (e >= N_EDGES) return;
    int src = ei[e];
    int dst = ei[N_EDGES + e];
    int pos = atomicAdd(&cursor[dst], 1);
    ssrc[pos] = src;
}

// ---------------------------------------------------------------------------
// Gather: h[n] = feat[n] + sum_{s in nbrs(n)} feat[s].
// 4 nodes per wave, 16 lanes per node, uint4 (8 bf16 = 16B) per lane.
// 4-edge unroll -> 4 outstanding 256B row reads per lane.
// ---------------------------------------------------------------------------
__global__ __launch_bounds__(256) void gather_kernel(const uint4* __restrict__ fb4,
                                                     const int* __restrict__ offs,
                                                     const int* __restrict__ ssrc,
                                                     uint4* __restrict__ hb4) {
    int wave = (blockIdx.x * 256 + threadIdx.x) >> 6;
    int lane = threadIdx.x & 63;
    int quad = lane >> 4;
    int l16 = lane & 15;
    int node = wave * 4 + quad;   // 12500 waves * 4 = 50000 exactly
    int beg = offs[node];
    int end = offs[node + 1];

    float a0, a1, a2, a3, a4, a5, a6, a7;
    uint4 own = fb4[node * 16 + l16];
    a0 = bflo(own.x); a1 = bfhi(own.x);
    a2 = bflo(own.y); a3 = bfhi(own.y);
    a4 = bflo(own.z); a5 = bfhi(own.z);
    a6 = bflo(own.w); a7 = bfhi(own.w);

    int j = beg;
    for (; j + 3 < end; j += 4) {
        int s0 = ssrc[j];
        int s1 = ssrc[j + 1];
        int s2 = ssrc[j + 2];
        int s3 = ssrc[j + 3];
        uint4 v0 = fb4[s0 * 16 + l16];
        uint4 v1 = fb4[s1 * 16 + l16];
        uint4 v2 = fb4[s2 * 16 + l16];
        uint4 v3 = fb4[s3 * 16 + l16];
        a0 += (bflo(v0.x) + bflo(v1.x)) + (bflo(v2.x) + bflo(v3.x));
        a1 += (bfhi(v0.x) + bfhi(v1.x)) + (bfhi(v2.x) + bfhi(v3.x));
        a2 += (bflo(v0.y) + bflo(v1.y)) + (bflo(v2.y) + bflo(v3.y));
        a3 += (bfhi(v0.y) + bfhi(v1.y)) + (bfhi(v2.y) + bfhi(v3.y));
        a4 += (bflo(v0.z) + bflo(v1.z)) + (bflo(v2.z) + bflo(v3.z));
        a5 += (bfhi(v0.z) + bfhi(v1.z)) + (bfhi(v2.z) + bfhi(v3.z));
        a6 += (bflo(v0.w) + bflo(v1.w)) + (bflo(v2.w) + bflo(v3.w));
        a7 += (bfhi(v0.w) + bfhi(v1.w)) + (bfhi(v2.w) + bfhi(v3.w));
    }
    for (; j < end; ++j) {
        uint4 v = fb4[ssrc[j] * 16 + l16];
        a0 += bflo(v.x); a1 += bfhi(v.x);
        a2 += bflo(v.y); a3 += bfhi(v.y);
        a4 += bflo(v.z); a5 += bfhi(v.z);
        a6 += bflo(v.w); a7 += bfhi(v.w);
    }

    uint4 o;
    o.x = f2bf(a0) | (f2bf(a1) << 16);
    o.y = f2bf(a2) | (f2bf(a3) << 16);
    o.z = f2bf(a4) | (f2bf(a5) << 16);
    o.w = f2bf(a6) | (f2bf(a7) << 16);
    hb4[node * 16 + l16] = o;
}

// ---------------------------------------------------------------------------
// Fused MLP: out = relu(relu(hb@W1+b1)@W2+b2), + BN column sum/sumsq.
// 64 rows/block, 4 waves x 16 rows. Per wave, GEMM1 output rows == GEMM2
// input rows, so no cross-wave exchange: h1 frag (C-layout) round-trips
// through the reused A-LDS buffer into A-layout with the same XOR swizzle.
// LDS: A 16KB + B1 32KB + B2 32KB = 80KB -> 2 blocks/CU.
// ---------------------------------------------------------------------------
__global__ __launch_bounds__(256) void mlp_kernel(
    const unsigned short* __restrict__ A,
    const unsigned short* __restrict__ Bt1, const unsigned short* __restrict__ Bt2,
    const float* __restrict__ bias1, const float* __restrict__ bias2,
    float* __restrict__ out, float* __restrict__ stats)
{
    __shared__ unsigned short Albs[64 * 128];    // h tile, then h1 tile
    __shared__ unsigned short B1lds[128 * 128];
    __shared__ unsigned short B2lds[128 * 128];

    const int tid = threadIdx.x;
    const int rowBase = blockIdx.x * 64;

    #pragma unroll
    for (int i = 0; i < 4; ++i) {  // A: 1024 16B granules
        int c = tid + i * 256;
        int row = c >> 4;
        int g = c & 15;
        uint4 v = make_uint4(0, 0, 0, 0);
        if (rowBase + row < N_NODES)
            v = *(const uint4*)&A[(rowBase + row) * 128 + g * 8];
        *(uint4*)&Albs[row * 128 + (g ^ (row & 15)) * 8] = v;
    }
    #pragma unroll
    for (int i = 0; i < 8; ++i) {  // B1 + B2: 2048 granules each
        int c = tid + i * 256;
        int row = c >> 4;
        int g = c & 15;
        int dst = row * 128 + (g ^ (row & 15)) * 8;
        int src = row * 128 + g * 8;
        *(uint4*)&B1lds[dst] = *(const uint4*)&Bt1[src];
        *(uint4*)&B2lds[dst] = *(const uint4*)&Bt2[src];
    }
    __syncthreads();

    const int lane = tid & 63;
    const int wid = tid >> 6;
    const int l15 = lane & 15;
    const int quad = lane >> 4;
    const int arow = wid * 16 + l15;

    // ---- GEMM1 ----
    floatx4 acc[8];
    #pragma unroll
    for (int n = 0; n < 8; ++n) acc[n] = (floatx4){0.f, 0.f, 0.f, 0.f};
    #pragma unroll
    for (int kc = 0; kc < 4; ++kc) {
        int ga = (kc * 4 + quad) ^ l15;
        short8 af = *(const short8*)&Albs[arow * 128 + ga * 8];
        #pragma unroll
        for (int n = 0; n < 8; ++n) {
            short8 bf = *(const short8*)&B1lds[(n * 16 + l15) * 128 + ga * 8];
            acc[n] = __builtin_amdgcn_mfma_f32_16x16x32_bf16(af, bf, acc[n], 0, 0, 0);
        }
    }

    // ReLU+bias, write h1 frag back into Albs in swizzled A-layout.
    // Each wave touches only its own 16 rows -> barrier is for lgkm ordering.
    __syncthreads();
    {
        const int rl0 = wid * 16 + quad * 4;  // local row of frag reg r
        #pragma unroll
        for (int n = 0; n < 8; ++n) {
            int col = n * 16 + l15;
            float b = bias1[col];
            int g = col >> 3;          // granule of col
            int o7 = col & 7;
            #pragma unroll
            for (int r = 0; r < 4; ++r) {
                int rl = rl0 + r;
                float v = fmaxf(acc[n][r] + b, 0.f);
                Albs[rl * 128 + ((g ^ (rl & 15)) * 8) + o7] = (unsigned short)f2bf(v);
            }
        }
    }
    __syncthreads();

    // ---- GEMM2 ----
    #pragma unroll
    for (int n = 0; n < 8; ++n) acc[n] = (floatx4){0.f, 0.f, 0.f, 0.f};
    #pragma unroll
    for (int kc = 0; kc < 4; ++kc) {
        int ga = (kc * 4 + quad) ^ l15;
        short8 af = *(const short8*)&Albs[arow * 128 + ga * 8];
        #pragma unroll
        for (int n = 0; n < 8; ++n) {
            short8 bf = *(const short8*)&B2lds[(n * 16 + l15) * 128 + ga * 8];
            acc[n] = __builtin_amdgcn_mfma_f32_16x16x32_bf16(af, bf, acc[n], 0, 0, 0);
        }
    }

    int r0 = rowBase + wid * 16 + quad * 4;
    float s[8], q[8];
    #pragma unroll
    for (int n = 0; n < 8; ++n) {
        s[n] = 0.f; q[n] = 0.f;
        int col = n * 16 + l15;
        float b = bias2[col];
        #pragma unroll
        for (int r = 0; r < 4; ++r) {
            int row = r0 + r;
            if (row < N_NODES) {
                float v = fmaxf(acc[n][r] + b, 0.f);
                out[row * 128 + col] = v;
                s[n] += v;
                q[n] += v * v;
            }
        }
    }

    #pragma unroll
    for (int n = 0; n < 8; ++n) {
        s[n] += __shfl_xor(s[n], 16);
        s[n] += __shfl_xor(s[n], 32);
        q[n] += __shfl_xor(q[n], 16);
        q[n] += __shfl_xor(q[n], 32);
    }
    __syncthreads();
    float* red = (float*)B1lds;  // [0..511]=sums [512..1023]=sqs
    if (lane < 16) {
        #pragma unroll
        for (int n = 0; n < 8; ++n) {
            red[wid * 128 + n * 16 + lane] = s[n];
            red[512 + wid * 128 + n * 16 + lane] = q[n];
        }
    }
    __syncthreads();
    if (tid < 128) {
        float ss = 0.f, qq = 0.f;
        #pragma unroll
        for (int w = 0; w < 4; ++w) {
            ss += red[w * 128 + tid];
            qq += red[512 + w * 128 + tid];
        }
        atomicAdd(&stats[tid], ss);
        atomicAdd(&stats[128 + tid], qq);
    }
}

// ---------------------------------------------------------------------------
// BatchNorm apply, in place on out
// ---------------------------------------------------------------------------
__global__ void bn_kernel(float* __restrict__ y,
                          const float* __restrict__ stats,
                          const float* __restrict__ gamma,
                          const float* __restrict__ beta)
{
    int gid = blockIdx.x * blockDim.x + threadIdx.x;
    const int n4 = N_NODES * D / 4;
    if (gid >= n4) return;
    int c0 = (gid << 2) & 127;
    const float inv_n = 1.0f / (float)N_NODES;
    float4 v = ((float4*)y)[gid];
    float4 s = *(const float4*)&stats[c0];
    float4 q = *(const float4*)&stats[128 + c0];
    float4 g = *(const float4*)&gamma[c0];
    float4 b = *(const float4*)&beta[c0];

    float m, var;
    m = s.x * inv_n; var = q.x * inv_n - m * m;
    v.x = (v.x - m) * rsqrtf(var + BN_EPS) * g.x + b.x;
    m = s.y * inv_n; var = q.y * inv_n - m * m;
    v.y = (v.y - m) * rsqrtf(var + BN_EPS) * g.y + b.y;
    m = s.z * inv_n; var = q.z * inv_n - m * m;
    v.z = (v.z - m) * rsqrtf(var + BN_EPS) * g.z + b.z;
    m = s.w * inv_n; var = q.w * inv_n - m * m;
    v.w = (v.w - m) * rsqrtf(var + BN_EPS) * g.w + b.w;

    ((float4*)y)[gid] = v;
}

// ---------------------------------------------------------------------------
extern "C" void kernel_launch(void* const* d_in, const int* in_sizes, int n_in,
                              void* d_out, int out_size, void* d_ws, size_t ws_size,
                              hipStream_t stream) {
    const float* feature = (const float*)d_in[0];
    const int*   ei      = (const int*)d_in[1];
    const float* W1      = (const float*)d_in[2];
    const float* b1      = (const float*)d_in[3];
    const float* W2      = (const float*)d_in[4];
    const float* b2      = (const float*)d_in[5];
    const float* gamma   = (const float*)d_in[6];
    const float* beta    = (const float*)d_in[7];
    float* out = (float*)d_out;

    unsigned*       featb = (unsigned*)d_ws;                       // 12.8 MB
    unsigned*       hb    = featb + N_NODES * 64;                  // 12.8 MB
    unsigned short* Wt1   = (unsigned short*)(hb + N_NODES * 64);  // 32 KB
    unsigned short* Wt2   = Wt1 + D * D;                           // 32 KB
    float*          stats = (float*)(Wt2 + D * D);                 // 1 KB
    int*            cnt   = (int*)(stats + 256);                   // 50000
    int*            offs  = cnt + N_NODES;                         // 50001
    int*            cursor= offs + N_NODES + 1;                    // 50000
    int*            ssrc  = cursor + N_NODES;                      // 600000
    int*            bsum  = ssrc + N_EDGES;                        // SCAN_BLOCKS

    prep_kernel<<<FEATC_BLOCKS + WPREP_BLOCKS + ZERO_BLOCKS, 256, 0, stream>>>(
        feature, featb, W1, W2, Wt1, Wt2, cnt, stats);
    hist_kernel<<<(N_EDGES + 255) / 256, 256, 0, stream>>>(ei, cnt);
    scanA_kernel<<<SCAN_BLOCKS, 1024, 0, stream>>>(cnt, offs, bsum);
    scanC_kernel<<<SCAN_BLOCKS, 1024, 0, stream>>>(offs, bsum, cursor);
    scatter_idx_kernel<<<(N_EDGES + 255) / 256, 256, 0, stream>>>(ei, cursor, ssrc);
    gather_kernel<<<N_NODES / 4 * 64 / 256, 256, 0, stream>>>(
        (const uint4*)featb, offs, ssrc, (uint4*)hb);
    mlp_kernel<<<(N_NODES + 63) / 64, 256, 0, stream>>>(
        (const unsigned short*)hb, Wt1, Wt2, b1, b2, out, stats);
    bn_kernel<<<(N_NODES * D / 4 + 255) / 256, 256, 0, stream>>>(out, stats, gamma, beta);
}